// Round 3
// baseline (343.024 us; speedup 1.0000x reference)
//
#include <hip/hip_runtime.h>

// CorrNeigh: out[b, i*7+j, h, w] = sum_c x[b,c,h,w] * y[b,c,h+i-3,w+j-3]
// B=8 C=128 H=W=256, K=7, PAD=3, fp32. Memory-bound (~640 MB HBM -> ~102 us).
//
// Round 3: ZERO shared state. No LDS, no __syncthreads, no atomics -> every
// output element is a pure wave-local function of x,y; replay divergence is
// impossible by construction.
//
//  - Block = 7 waves (448 thr), tile = 64w x 8h. Wave i handles dy=i.
//  - Lane: lw = lane&7 (w-octet), lr = lane>>3 (row). Lane owns 8 pixels.
//  - Lane loads its own ALIGNED y octet (2x float4) for row h0+lr+i-3;
//    the +-3 window halo comes from lane+-1 via 6 __shfl; tile-edge halo
//    via one predicated aligned float4 on lanes lw==0 / lw==7.
//  - Out-of-image rows/cols -> multiplicative 0/1 masks (pad semantics).
//  - x octet loaded per wave straight from global (L1 serves 7x reuse).
//  - XCD-chunked swizzle: one batch image per XCD -> vertical halo rows
//    stay L2-resident.

#define Bq 8
#define Cq 128
#define Hq 256
#define Wq 256
#define Kq 7
#define TILE_H 8
#define TILE_W 64
#define NTHR 448

__global__ __launch_bounds__(NTHR)
void corr7_kernel(const float* __restrict__ x, const float* __restrict__ y,
                  float* __restrict__ out)
{
    const int t    = threadIdx.x;
    const int wave = t >> 6;        // dy index i (0..6)
    const int lane = t & 63;
    const int lw   = lane & 7;      // w-octet
    const int lr   = lane >> 3;     // row within tile (0..7)

    // XCD-chunked swizzle: consecutive dispatch ids round-robin XCDs;
    // map so XCD k gets tiles [k*128, k*128+128) = one full batch image.
    int bid = (int)blockIdx.x;
    bid = (bid & 7) * 128 + (bid >> 3);

    const int tw = bid & 3;          // 4 w-tiles
    const int th = (bid >> 2) & 31;  // 32 h-tiles
    const int b  = bid >> 7;         // batch

    const int h0 = th * TILE_H;
    const int w0 = tw * TILE_W;

    const size_t cs   = (size_t)Hq * Wq;       // channel stride
    const size_t base = (size_t)b * Cq * cs;   // batch base

    // x row (output rows are always in-image)
    const float* xp = x + base + (size_t)(h0 + lr) * Wq + (w0 + 8 * lw);

    // this wave's single y row: gy = h0 + lr + wave - 3  (range -3..+10 off tile)
    const int gy    = h0 + lr + wave - 3;
    const bool rowok = (unsigned)gy < (unsigned)Hq;
    const float rowm = rowok ? 1.f : 0.f;
    const int gyc   = gy < 0 ? 0 : (gy > Hq - 1 ? Hq - 1 : gy);
    const float* yrow0 = y + base + (size_t)gyc * Wq;   // + c*cs per channel

    const int lanem1 = (lane + 63) & 63;
    const int lanep1 = (lane + 1) & 63;
    const bool isL = (lw == 0);
    const bool isR = (lw == 7);
    // edge-halo: left cols w0-3..w0-1 (exist iff tw>0), right cols w0+64..66
    // (exist iff tw<3). Loads use always-valid aligned addresses; validity
    // (incl. row) applied as a 0/1 mask.
    const float lm = (rowok && tw > 0) ? 1.f : 0.f;
    const float rm = (rowok && tw < 3) ? 1.f : 0.f;
    const int loff = (tw > 0) ? (w0 - 4) : w0;        // aligned float4 addr
    const int roff = (tw < 3) ? (w0 + TILE_W) : w0;   // aligned float4 addr

    float acc[Kq][8];
#pragma unroll
    for (int j = 0; j < Kq; ++j)
#pragma unroll
        for (int r = 0; r < 8; ++r) acc[j][r] = 0.f;

    for (int c = 0; c < Cq; ++c) {
        const size_t co = (size_t)c * cs;

        // x octet (aligned)
        const float4 x0 = *(const float4*)(xp + co);
        const float4 x1 = *(const float4*)(xp + co + 4);

        // own y octet (aligned), then row mask (pad rows -> 0)
        const float* yr = yrow0 + co;
        float4 y0 = *(const float4*)(yr + w0 + 8 * lw);
        float4 y1 = *(const float4*)(yr + w0 + 8 * lw + 4);
        y0.x *= rowm; y0.y *= rowm; y0.z *= rowm; y0.w *= rowm;
        y1.x *= rowm; y1.y *= rowm; y1.z *= rowm; y1.w *= rowm;

        // edge-halo float4 (only lanes lw==0 / lw==7 load; exec-masked)
        float4 hv = make_float4(0.f, 0.f, 0.f, 0.f);
        if (isL) hv = *(const float4*)(yr + loff);   // .y,.z,.w = cols w0-3..-1
        if (isR) hv = *(const float4*)(yr + roff);   // .x,.y,.z = cols w0+64..66

        // window halo from neighbor lanes (same lr => same rowok, already masked)
        float l0 = __shfl(y1.y, lanem1);   // neighbor octet elem 5
        float l1 = __shfl(y1.z, lanem1);   // elem 6
        float l2 = __shfl(y1.w, lanem1);   // elem 7
        float r0 = __shfl(y0.x, lanep1);   // neighbor octet elem 0
        float r1 = __shfl(y0.y, lanep1);   // elem 1
        float r2 = __shfl(y0.z, lanep1);   // elem 2
        if (isL) { l0 = hv.y * lm; l1 = hv.z * lm; l2 = hv.w * lm; }
        if (isR) { r0 = hv.x * rm; r1 = hv.y * rm; r2 = hv.z * rm; }

        // 14-float sliding window -> 7x8 FMAs
        const float yw[14] = {l0, l1, l2,
                              y0.x, y0.y, y0.z, y0.w,
                              y1.x, y1.y, y1.z, y1.w,
                              r0, r1, r2};
        const float xv[8] = {x0.x, x0.y, x0.z, x0.w, x1.x, x1.y, x1.z, x1.w};
#pragma unroll
        for (int j = 0; j < Kq; ++j)
#pragma unroll
            for (int r = 0; r < 8; ++r)
                acc[j][r] = fmaf(xv[r], yw[r + j], acc[j][r]);
    }

    // epilogue: this wave writes k-planes wave*7 .. wave*7+6
    size_t obase = (((size_t)b * (Kq * Kq) + (size_t)wave * Kq) * Hq
                    + (h0 + lr)) * Wq + (w0 + 8 * lw);
#pragma unroll
    for (int j = 0; j < Kq; ++j) {
        float4 o0 = {acc[j][0], acc[j][1], acc[j][2], acc[j][3]};
        float4 o1 = {acc[j][4], acc[j][5], acc[j][6], acc[j][7]};
        *(float4*)(out + obase)     = o0;
        *(float4*)(out + obase + 4) = o1;
        obase += cs;  // next k-plane
    }
}

extern "C" void kernel_launch(void* const* d_in, const int* in_sizes, int n_in,
                              void* d_out, int out_size, void* d_ws, size_t ws_size,
                              hipStream_t stream) {
    const float* x = (const float*)d_in[0];
    const float* y = (const float*)d_in[1];
    float* out = (float*)d_out;

    dim3 grid(Bq * 32 * 4);   // 1024 tiles: 8 batches x 32 h x 4 w
    dim3 block(NTHR);
    hipLaunchKernelGGL(corr7_kernel, grid, block, 0, stream, x, y, out);
}